// Round 1
// baseline (26.342 us; speedup 1.0000x reference)
//
#include <hip/hip_runtime.h>

#define B_SZ 8
#define P_SZ 24
#define H_SZ 448
#define W_SZ 448
#define HWPIX (H_SZ * W_SZ)
#define NUM_CLS 19

__global__ void zero_kernel(float4* __restrict__ out, int n4) {
    int i = blockIdx.x * blockDim.x + threadIdx.x;
    int stride = gridDim.x * blockDim.x;
    float4 z = make_float4(0.f, 0.f, 0.f, 0.f);
    for (; i < n4; i += stride) out[i] = z;
}

__global__ void paint_kernel(const float* __restrict__ coords, float* __restrict__ out) {
    int bp = blockIdx.x;              // b*P + p
    int b = bp / P_SZ;
    const float* c = coords + (size_t)bp * 3;
    float rf = c[0], cf = c[1];
    if (fmaxf(rf, cf) < 0.0f) return;     // valid = max(pts) >= 0
    int cls = (int)c[2];
    int row = (int)rf, col = (int)cf;

    int t = threadIdx.x;
    if (t >= 121) return;                  // 11x11 bounding box, r <= 5
    int dy = t / 11 - 5;
    int dx = t % 11 - 5;
    if (dy * dy + dx * dx > 25) return;    // DISK_R2 = 25
    int y = row + dy;
    int x = col + dx;
    if ((unsigned)y >= (unsigned)H_SZ || (unsigned)x >= (unsigned)W_SZ) return;
    out[((size_t)b * NUM_CLS + cls) * HWPIX + (size_t)y * W_SZ + x] = 255.0f;
}

extern "C" void kernel_launch(void* const* d_in, const int* in_sizes, int n_in,
                              void* d_out, int out_size, void* d_ws, size_t ws_size,
                              hipStream_t stream) {
    const float* coords = (const float*)d_in[1];   // (B, P, 3) f32
    float* out = (float*)d_out;                    // (B, NUM_CLS, H, W) f32

    int n4 = out_size / 4;                         // out_size = 30,507,008 (div by 4)
    zero_kernel<<<2048, 256, 0, stream>>>((float4*)out, n4);
    paint_kernel<<<B_SZ * P_SZ, 128, 0, stream>>>(coords, out);
}

// Round 2
// 21.872 us; speedup vs baseline: 1.2044x; 1.2044x over previous
//
#include <hip/hip_runtime.h>

#define B_SZ 8
#define P_SZ 24
#define H_SZ 448
#define W_SZ 448
#define NUM_CLS 19
#define W4 (W_SZ / 4)                 // 112 float4 per row
#define CH4 (H_SZ * W_SZ / 4)        // 50176 float4 per channel
#define THREADS 256
#define F4_PER_THREAD 2
#define CHUNK4 (THREADS * F4_PER_THREAD)       // 512 float4 per block
#define BLOCKS_PER_CH (CH4 / CHUNK4)           // 98 (exact)

__global__ __launch_bounds__(THREADS) void fused_distmap_kernel(
        const float* __restrict__ coords, float4* __restrict__ out) {
    int ch = blockIdx.x / BLOCKS_PER_CH;       // b * NUM_CLS + cls
    int chunk = blockIdx.x % BLOCKS_PER_CH;
    int b = ch / NUM_CLS;
    int cls = ch % NUM_CLS;

    __shared__ float s_r[P_SZ];
    __shared__ float s_c[P_SZ];
    __shared__ int s_cnt;
    if (threadIdx.x == 0) s_cnt = 0;
    __syncthreads();
    if (threadIdx.x < P_SZ) {
        const float* c = coords + ((size_t)b * P_SZ + threadIdx.x) * 3;
        float rf = c[0], cf = c[1];
        int pcls = (int)c[2];
        // valid = max(r,c) >= 0 ; only points of this channel's class matter
        if (pcls == cls && fmaxf(rf, cf) >= 0.0f) {
            int slot = atomicAdd(&s_cnt, 1);
            s_r[slot] = rf;
            s_c[slot] = cf;
        }
    }
    __syncthreads();
    int cnt = s_cnt;

    size_t chbase = (size_t)ch * CH4;
    int idx0 = chunk * CHUNK4 + threadIdx.x;   // first in-channel float4 index

    if (cnt == 0) {
        float4 z = make_float4(0.f, 0.f, 0.f, 0.f);
        #pragma unroll
        for (int u = 0; u < F4_PER_THREAD; ++u)
            out[chbase + idx0 + u * THREADS] = z;
        return;
    }

    #pragma unroll
    for (int u = 0; u < F4_PER_THREAD; ++u) {
        int idx4 = idx0 + u * THREADS;
        float y  = (float)(idx4 / W4);
        float x0 = (float)((idx4 % W4) * 4);
        float4 v = make_float4(0.f, 0.f, 0.f, 0.f);
        for (int p = 0; p < cnt; ++p) {
            float dr  = y - s_r[p];
            float dr2 = dr * dr;
            float dc  = x0 - s_c[p];
            if (dr2 + dc * dc                   <= 25.f) v.x = 255.f;
            if (dr2 + (dc+1.f) * (dc+1.f)       <= 25.f) v.y = 255.f;
            if (dr2 + (dc+2.f) * (dc+2.f)       <= 25.f) v.z = 255.f;
            if (dr2 + (dc+3.f) * (dc+3.f)       <= 25.f) v.w = 255.f;
        }
        out[chbase + idx4] = v;
    }
}

extern "C" void kernel_launch(void* const* d_in, const int* in_sizes, int n_in,
                              void* d_out, int out_size, void* d_ws, size_t ws_size,
                              hipStream_t stream) {
    const float* coords = (const float*)d_in[1];   // (B, P, 3) f32
    float4* out = (float4*)d_out;                  // (B, NUM_CLS, H, W) f32

    int grid = B_SZ * NUM_CLS * BLOCKS_PER_CH;     // 14896
    fused_distmap_kernel<<<grid, THREADS, 0, stream>>>(coords, out);
}